// Round 1
// baseline (2063.546 us; speedup 1.0000x reference)
//
#include <hip/hip_runtime.h>
#include <math.h>

// DynamicConv on MI355X — round 1: correct fp32 pipeline.
// Stages: pool -> attn softmax -> combine weights (per batch) -> direct 3x3 conv
//         -> BN stats (one block per channel, deterministic) -> BN+SiLU in place.
// Conv: block = (h row, 64-o block, b); thread = 4o x 4w; LDS x rows + weights.
// fp32 vector floor for the conv is ~491 us (77.3 GFLOP @ 157 TF).

#define B_ 16
#define C_ 256
#define O_ 256
#define K_ 4
#define HW_ 4096          // 64*64
#define PLANE_F4 1024     // 4096/4
#define WPERK 589824      // O_*C_*9
#define WPERK_F4 147456

// ---------------- pool: mean over H*W per (b,c) ----------------
__global__ __launch_bounds__(256) void pool_kernel(const float4* __restrict__ x4,
                                                   float* __restrict__ pooled) {
    int bc = blockIdx.x;                       // 0..4095
    const float4* p = x4 + (size_t)bc * PLANE_F4;
    float s = 0.f;
    for (int i = threadIdx.x; i < PLANE_F4; i += 256) {
        float4 v = p[i];
        s += v.x + v.y + v.z + v.w;
    }
    for (int off = 32; off; off >>= 1) s += __shfl_down(s, off);
    __shared__ float partial[4];
    if ((threadIdx.x & 63) == 0) partial[threadIdx.x >> 6] = s;
    __syncthreads();
    if (threadIdx.x == 0)
        pooled[bc] = (partial[0] + partial[1] + partial[2] + partial[3]) * (1.f / 4096.f);
}

// ---------------- attn: logits + softmax over K=4 ----------------
__global__ void attn_kernel(const float* __restrict__ pooled,
                            const float* __restrict__ attn_w,
                            float* __restrict__ attn) {
    int tid = threadIdx.x;                     // 64 threads
    int b = tid >> 2, k = tid & 3;
    float s = 0.f;
    for (int c = 0; c < C_; ++c) s += pooled[b * C_ + c] * attn_w[k * C_ + c];
    __shared__ float lg[16][4];
    lg[b][k] = s;
    __syncthreads();
    float m = fmaxf(fmaxf(lg[b][0], lg[b][1]), fmaxf(lg[b][2], lg[b][3]));
    float den = expf(lg[b][0] - m) + expf(lg[b][1] - m) +
                expf(lg[b][2] - m) + expf(lg[b][3] - m);
    attn[tid] = expf(s - m) / den;
}

// ---------------- combine: wcomb[b,o,c,3,3] = sum_k attn[b,k]*dyn[k,o,c,3,3] ----------------
__global__ __launch_bounds__(256) void combine_kernel(const float4* __restrict__ dyn,
                                                      const float* __restrict__ attn,
                                                      float4* __restrict__ wcomb) {
    const int total = B_ * WPERK_F4;           // 2359296
    for (int i = blockIdx.x * 256 + threadIdx.x; i < total; i += gridDim.x * 256) {
        int b = i / WPERK_F4;
        int j = i - b * WPERK_F4;
        float a0 = attn[b * 4 + 0], a1 = attn[b * 4 + 1],
              a2 = attn[b * 4 + 2], a3 = attn[b * 4 + 3];
        float4 d0 = dyn[j];
        float4 d1 = dyn[WPERK_F4 + j];
        float4 d2 = dyn[2 * WPERK_F4 + j];
        float4 d3 = dyn[3 * WPERK_F4 + j];
        float4 r;
        r.x = a0 * d0.x + a1 * d1.x + a2 * d2.x + a3 * d3.x;
        r.y = a0 * d0.y + a1 * d1.y + a2 * d2.y + a3 * d3.y;
        r.z = a0 * d0.z + a1 * d1.z + a2 * d2.z + a3 * d3.z;
        r.w = a0 * d0.w + a1 * d1.w + a2 * d2.w + a3 * d3.w;
        wcomb[i] = r;
    }
}

// ---------------- conv: direct 3x3, per-batch combined weights ----------------
// grid (h=64, o_blk=4, b=16), block 256. Thread tile: 4 o x 4 w.
// OTF=true combines weights on the fly from dyn_kernels (ws too small fallback).
template <bool OTF>
__global__ __launch_bounds__(256, 2) void conv_kernel(const float* __restrict__ x,
                                                      const float* __restrict__ wsrc,
                                                      const float* __restrict__ attn,
                                                      float* __restrict__ out) {
    __shared__ __align__(16) float xs[8][3][72];   // [c][row][w+1], w=-1..64
    __shared__ __align__(16) float wsh[64 * 100];  // per-o stride 100 floats (16B rows, 2-way banks)

    const int h   = blockIdx.x;
    const int ob  = blockIdx.y * 64;
    const int b   = blockIdx.z;
    const int tid = threadIdx.x;
    const int o_idx = tid >> 4;        // 0..15
    const int w0    = (tid & 15) * 4;  // 0..60

    float a0 = 0.f, a1 = 0.f, a2 = 0.f, a3 = 0.f;
    if (OTF) {
        a0 = attn[b * 4 + 0]; a1 = attn[b * 4 + 1];
        a2 = attn[b * 4 + 2]; a3 = attn[b * 4 + 3];
    }

    const float* xb = x + (size_t)b * (C_ * HW_);
    const float* wb = OTF ? (wsrc + (size_t)ob * 2304)
                          : (wsrc + (size_t)b * WPERK + (size_t)ob * 2304);

    float acc[4][4];
#pragma unroll
    for (int i = 0; i < 4; ++i)
#pragma unroll
        for (int j = 0; j < 4; ++j) acc[i][j] = 0.f;

    for (int cb = 0; cb < C_; cb += 8) {
        __syncthreads();
        // stage x: 8 channels x 3 rows x 66 (zero-padded)
        for (int idx = tid; idx < 8 * 3 * 66; idx += 256) {
            int c = idx / 198, rem = idx - c * 198;
            int r = rem / 66, wi = rem - r * 66;
            int hh = h - 1 + r, ww = wi - 1;
            float v = 0.f;
            if ((unsigned)hh < 64u && (unsigned)ww < 64u)
                v = xb[(size_t)(cb + c) * HW_ + hh * 64 + ww];
            xs[c][r][wi] = v;
        }
        // stage weights: 64 o x 8 c x 9 taps
        for (int idx = tid; idx < 64 * 72; idx += 256) {
            int o = idx / 72, j = idx - o * 72;
            int c = j / 9, t = j - c * 9;
            size_t gi = (size_t)o * 2304 + (size_t)(cb + c) * 9 + t;
            float v;
            if (OTF)
                v = a0 * wb[gi] + a1 * wb[WPERK + gi] +
                    a2 * wb[2 * WPERK + gi] + a3 * wb[3 * WPERK + gi];
            else
                v = wb[gi];
            wsh[o * 100 + c * 12 + t] = v;
        }
        __syncthreads();
#pragma unroll
        for (int cc = 0; cc < 8; ++cc) {
            float xr[3][6];
#pragma unroll
            for (int r = 0; r < 3; ++r) {
                float4 a = *(const float4*)&xs[cc][r][w0];
                float2 b2 = *(const float2*)&xs[cc][r][w0 + 4];
                xr[r][0] = a.x; xr[r][1] = a.y; xr[r][2] = a.z; xr[r][3] = a.w;
                xr[r][4] = b2.x; xr[r][5] = b2.y;
            }
#pragma unroll
            for (int oo = 0; oo < 4; ++oo) {
                const float* wp = &wsh[(o_idx * 4 + oo) * 100 + cc * 12];
                float4 wA = *(const float4*)wp;
                float4 wB = *(const float4*)(wp + 4);
                float w8 = wp[8];
#pragma unroll
                for (int ww = 0; ww < 4; ++ww) {
                    acc[oo][ww] += wA.x * xr[0][ww]     + wA.y * xr[0][ww + 1] + wA.z * xr[0][ww + 2]
                                 + wA.w * xr[1][ww]     + wB.x * xr[1][ww + 1] + wB.y * xr[1][ww + 2]
                                 + wB.z * xr[2][ww]     + wB.w * xr[2][ww + 1] + w8   * xr[2][ww + 2];
                }
            }
        }
    }
    float* op = out + ((size_t)b * O_ + ob) * HW_ + h * 64;
#pragma unroll
    for (int oo = 0; oo < 4; ++oo) {
        float4 v = make_float4(acc[oo][0], acc[oo][1], acc[oo][2], acc[oo][3]);
        *(float4*)&op[(size_t)(o_idx * 4 + oo) * HW_ + w0] = v;
    }
}

// ---------------- BN stats: one block per channel (deterministic, no atomics) ----------------
__global__ __launch_bounds__(256) void stats_kernel(const float4* __restrict__ out4,
                                                    const float* __restrict__ gamma,
                                                    float* __restrict__ mean,
                                                    float* __restrict__ inv) {
    int o = blockIdx.x;
    float s = 0.f, s2 = 0.f;
    for (int b = 0; b < B_; ++b) {
        const float4* p = out4 + ((size_t)b * O_ + o) * PLANE_F4;
        for (int i = threadIdx.x; i < PLANE_F4; i += 256) {
            float4 v = p[i];
            s  += v.x + v.y + v.z + v.w;
            s2 += v.x * v.x + v.y * v.y + v.z * v.z + v.w * v.w;
        }
    }
    for (int off = 32; off; off >>= 1) {
        s  += __shfl_down(s, off);
        s2 += __shfl_down(s2, off);
    }
    __shared__ float ps[4], ps2[4];
    int w = threadIdx.x >> 6;
    if ((threadIdx.x & 63) == 0) { ps[w] = s; ps2[w] = s2; }
    __syncthreads();
    if (threadIdx.x == 0) {
        float S = ps[0] + ps[1] + ps[2] + ps[3];
        float S2 = ps2[0] + ps2[1] + ps2[2] + ps2[3];
        float m = S * (1.f / 65536.f);
        float var = S2 * (1.f / 65536.f) - m * m;
        mean[o] = m;
        inv[o] = gamma[o] * rsqrtf(var + 1e-3f);
    }
}

// ---------------- BN apply + SiLU, in place ----------------
__global__ __launch_bounds__(256) void bn_silu_kernel(float4* __restrict__ out4,
                                                      const float* __restrict__ mean,
                                                      const float* __restrict__ inv,
                                                      const float* __restrict__ beta) {
    const int total = B_ * O_ * PLANE_F4;      // 4194304
    for (int i = blockIdx.x * 256 + threadIdx.x; i < total; i += gridDim.x * 256) {
        int plane = i >> 10;                   // b*256+o
        int o = plane & 255;
        float m = mean[o], iv = inv[o], bt = beta[o];
        float4 v = out4[i];
        float u;
        u = (v.x - m) * iv + bt; v.x = u / (1.f + expf(-u));
        u = (v.y - m) * iv + bt; v.y = u / (1.f + expf(-u));
        u = (v.z - m) * iv + bt; v.z = u / (1.f + expf(-u));
        u = (v.w - m) * iv + bt; v.w = u / (1.f + expf(-u));
        out4[i] = v;
    }
}

extern "C" void kernel_launch(void* const* d_in, const int* in_sizes, int n_in,
                              void* d_out, int out_size, void* d_ws, size_t ws_size,
                              hipStream_t stream) {
    const float* x      = (const float*)d_in[0];
    const float* dyn    = (const float*)d_in[1];
    const float* attn_w = (const float*)d_in[2];
    const float* gamma  = (const float*)d_in[3];
    const float* beta   = (const float*)d_in[4];
    float* out = (float*)d_out;
    float* ws  = (float*)d_ws;

    float* pooled = ws;             // 4096
    float* attn   = ws + 4096;      // 64
    float* mean   = ws + 4224;      // 256
    float* inv    = ws + 4480;      // 256
    float* wcomb  = ws + 4736;      // 9437184 (37.7 MB)

    const bool precomb =
        ws_size >= (size_t)(4736 + (size_t)B_ * WPERK) * sizeof(float);

    pool_kernel<<<4096, 256, 0, stream>>>((const float4*)x, pooled);
    attn_kernel<<<1, 64, 0, stream>>>(pooled, attn_w, attn);
    if (precomb) {
        combine_kernel<<<4096, 256, 0, stream>>>((const float4*)dyn, attn, (float4*)wcomb);
        conv_kernel<false><<<dim3(64, 4, 16), 256, 0, stream>>>(x, wcomb, attn, out);
    } else {
        conv_kernel<true><<<dim3(64, 4, 16), 256, 0, stream>>>(x, dyn, attn, out);
    }
    stats_kernel<<<256, 256, 0, stream>>>((const float4*)out, gamma, mean, inv);
    bn_silu_kernel<<<4096, 256, 0, stream>>>((float4*)out, mean, inv, beta);
}

// Round 2
// 518.665 us; speedup vs baseline: 3.9786x; 3.9786x over previous
//
#include <hip/hip_runtime.h>
#include <math.h>

// DynamicConv on MI355X — round 2: MFMA conv with split-precision bf16 (hi+lo).
// conv-as-GEMM per batch: M=256(o), N=4096(hw), K=2304(c*9).
// x staged in LDS as [row][w][c] (c innermost, 40-slot/80B pixel stride:
// 16B-aligned, conflict-free octets) so all 9 taps reuse one tile and the
// B-fragment is one ds_read_b128. W pre-combined+split+transposed to
// [b][o][t][c] bf16 hi/lo (fits the 37.77MB ws exactly).
// 3 MFMA passes (hh,hl,lh) into one fp32 acc -> error ~2^-16, absmax ~= fp32 baseline.

#define B_ 16
#define C_ 256
#define O_ 256
#define HW_ 4096          // 64*64
#define PLANE_F4 1024
#define WPERK 589824      // O_*C_*9
#define XS_PX 40          // bf16 slots per pixel in LDS x tile (32 ch + 8 pad)

typedef short bf16x8 __attribute__((ext_vector_type(8)));
typedef float f32x4 __attribute__((ext_vector_type(4)));

__device__ __forceinline__ unsigned short f2bf(float f) {
    unsigned u = __float_as_uint(f);
    u += 0x7FFFu + ((u >> 16) & 1u);
    return (unsigned short)(u >> 16);
}
__device__ __forceinline__ float bf2f(unsigned short h) {
    return __uint_as_float((unsigned)h << 16);
}

// ---------------- pool: mean over H*W per (b,c) ----------------
__global__ __launch_bounds__(256) void pool_kernel(const float4* __restrict__ x4,
                                                   float* __restrict__ pooled) {
    int bc = blockIdx.x;
    const float4* p = x4 + (size_t)bc * PLANE_F4;
    float s = 0.f;
    for (int i = threadIdx.x; i < PLANE_F4; i += 256) {
        float4 v = p[i];
        s += v.x + v.y + v.z + v.w;
    }
    for (int off = 32; off; off >>= 1) s += __shfl_down(s, off);
    __shared__ float partial[4];
    if ((threadIdx.x & 63) == 0) partial[threadIdx.x >> 6] = s;
    __syncthreads();
    if (threadIdx.x == 0)
        pooled[bc] = (partial[0] + partial[1] + partial[2] + partial[3]) * (1.f / 4096.f);
}

// ---------------- attn: logits + softmax over K=4 ----------------
__global__ void attn_kernel(const float* __restrict__ pooled,
                            const float* __restrict__ attn_w,
                            float* __restrict__ attn) {
    int tid = threadIdx.x;                     // 64 threads
    int b = tid >> 2, k = tid & 3;
    float s = 0.f;
    for (int c = 0; c < C_; ++c) s += pooled[b * C_ + c] * attn_w[k * C_ + c];
    __shared__ float lg[16][4];
    lg[b][k] = s;
    __syncthreads();
    float m = fmaxf(fmaxf(lg[b][0], lg[b][1]), fmaxf(lg[b][2], lg[b][3]));
    float den = expf(lg[b][0] - m) + expf(lg[b][1] - m) +
                expf(lg[b][2] - m) + expf(lg[b][3] - m);
    attn[tid] = expf(s - m) / den;
}

// ---------------- wtrans: combine over k, split hi/lo, transpose to [b][o][t][c] ----------------
__global__ __launch_bounds__(256) void wtrans_kernel(const float* __restrict__ dyn,
                                                     const float* __restrict__ attn,
                                                     unsigned short* __restrict__ wt_hi,
                                                     unsigned short* __restrict__ wt_lo) {
    int idx = blockIdx.x * 256 + threadIdx.x;   // (b,o,c), c fastest -> coalesced
    int b = idx >> 16;
    int o = (idx >> 8) & 255;
    int c = idx & 255;
    float a0 = attn[b * 4 + 0], a1 = attn[b * 4 + 1],
          a2 = attn[b * 4 + 2], a3 = attn[b * 4 + 3];
    const float* p0 = dyn + ((size_t)o * 256 + c) * 9;   // [k][o][c][t], k stride WPERK
    float v[9];
#pragma unroll
    for (int t = 0; t < 9; ++t)
        v[t] = a0 * p0[t] + a1 * p0[WPERK + t] + a2 * p0[2 * WPERK + t] + a3 * p0[3 * WPERK + t];
    size_t obase = ((size_t)(b * 256 + o) * 9) * 256 + c;
#pragma unroll
    for (int t = 0; t < 9; ++t) {
        float f = v[t];
        unsigned short h = f2bf(f);
        unsigned short l = f2bf(f - bf2f(h));
        wt_hi[obase + (size_t)t * 256] = h;
        wt_lo[obase + (size_t)t * 256] = l;
    }
}

// ---------------- conv via MFMA ----------------
// grid (p_tile=32, o_tile=2, b=16), 256 thr = 4 waves. WG tile 128o x 128p (2 h-rows).
// wave tile 64o x 64p: 4x4 fragments of 16x16, K loop = 8 cb-chunks x 9 taps x K32.
__global__ __launch_bounds__(256, 2) void conv_mfma_kernel(const float* __restrict__ x,
        const unsigned short* __restrict__ wt_hi,
        const unsigned short* __restrict__ wt_lo,
        float* __restrict__ out) {
    __shared__ __align__(16) unsigned short xs_hi[4 * 66 * XS_PX];
    __shared__ __align__(16) unsigned short xs_lo[4 * 66 * XS_PX];

    const int h0   = blockIdx.x * 2;
    const int ob   = blockIdx.y * 128;
    const int b    = blockIdx.z;
    const int tid  = threadIdx.x;
    const int lane = tid & 63;
    const int wid  = tid >> 6;
    const int lo16 = lane & 15;
    const int g    = lane >> 4;
    const int wo   = ob + (wid >> 1) * 64;   // wave o-base
    const int hr   = h0 + (wid & 1);         // wave h-row

    const float* xb = x + (size_t)b * (C_ * HW_);

    f32x4 acc[4][4];
#pragma unroll
    for (int i = 0; i < 4; ++i)
#pragma unroll
        for (int j = 0; j < 4; ++j) acc[i][j] = (f32x4){0.f, 0.f, 0.f, 0.f};

    // per-thread bases
    const unsigned short* wph = wt_hi + ((size_t)(b * 256 + wo + lo16) * 9) * 256 + g * 8;
    const unsigned short* wpl = wt_lo + ((size_t)(b * 256 + wo + lo16) * 9) * 256 + g * 8;
    const unsigned short* xh = xs_hi + ((wid & 1) * 66 + lo16) * XS_PX + g * 8;
    const unsigned short* xl = xs_lo + ((wid & 1) * 66 + lo16) * XS_PX + g * 8;

#pragma unroll 1
    for (int cb = 0; cb < 256; cb += 32) {
        __syncthreads();
        // stage x: rows h0-1..h0+2, w -1..64, channels cb..cb+31 -> [row][w][c]
        for (int it = tid; it < 4 * 264; it += 256) {
            int cchunk = it / 264;           // 0..3 (8 channels each)
            int px = it - cchunk * 264;      // r*66 + w
            int r = px / 66;
            int w = px - r * 66;
            int hh = h0 - 1 + r;
            int ww = w - 1;
            unsigned hi_w[4] = {0u, 0u, 0u, 0u}, lo_w[4] = {0u, 0u, 0u, 0u};
            if ((unsigned)hh < 64u && (unsigned)ww < 64u) {
                const float* xp = xb + (size_t)(cb + cchunk * 8) * HW_ + hh * 64 + ww;
#pragma unroll
                for (int i = 0; i < 8; ++i) {
                    float f = xp[(size_t)i * HW_];
                    unsigned short h = f2bf(f);
                    unsigned short l = f2bf(f - bf2f(h));
                    hi_w[i >> 1] |= (unsigned)h << ((i & 1) * 16);
                    lo_w[i >> 1] |= (unsigned)l << ((i & 1) * 16);
                }
            }
            int off = px * XS_PX + cchunk * 8;
            *(uint4*)&xs_hi[off] = make_uint4(hi_w[0], hi_w[1], hi_w[2], hi_w[3]);
            *(uint4*)&xs_lo[off] = make_uint4(lo_w[0], lo_w[1], lo_w[2], lo_w[3]);
        }
        __syncthreads();

#pragma unroll
        for (int t = 0; t < 9; ++t) {
            const int dh = t / 3, dw = t % 3;
            // B fragments: 8 consecutive channels at one (shifted) pixel
            bf16x8 bh[4], bl[4];
#pragma unroll
            for (int nf = 0; nf < 4; ++nf) {
                const int xoff = (dh * 66 + dw + nf * 16) * XS_PX;
                bh[nf] = *(const bf16x8*)&xh[xoff];
                bl[nf] = *(const bf16x8*)&xl[xoff];
            }
#pragma unroll
            for (int mf = 0; mf < 4; ++mf) {
                const size_t woff = (size_t)(mf * 16 * 9 + t) * 256 + cb;
                bf16x8 ah = *(const bf16x8*)(wph + woff);
                bf16x8 al = *(const bf16x8*)(wpl + woff);
#pragma unroll
                for (int nf = 0; nf < 4; ++nf) {
                    acc[mf][nf] = __builtin_amdgcn_mfma_f32_16x16x32_bf16(ah, bh[nf], acc[mf][nf], 0, 0, 0);
                    acc[mf][nf] = __builtin_amdgcn_mfma_f32_16x16x32_bf16(ah, bl[nf], acc[mf][nf], 0, 0, 0);
                    acc[mf][nf] = __builtin_amdgcn_mfma_f32_16x16x32_bf16(al, bh[nf], acc[mf][nf], 0, 0, 0);
                }
            }
        }
    }

    // epilogue: D layout col=lane&15 (p), row=(lane>>4)*4+r (o)
    float* op = out + ((size_t)b * 256 + wo) * HW_ + (size_t)hr * 64;
#pragma unroll
    for (int mf = 0; mf < 4; ++mf)
#pragma unroll
        for (int nf = 0; nf < 4; ++nf) {
            f32x4 a = acc[mf][nf];
#pragma unroll
            for (int r = 0; r < 4; ++r)
                op[(size_t)(mf * 16 + g * 4 + r) * HW_ + nf * 16 + lo16] = a[r];
        }
}

// ---------------- fp32 OTF conv fallback (ws too small) ----------------
template <bool OTF>
__global__ __launch_bounds__(256, 2) void conv_kernel(const float* __restrict__ x,
                                                      const float* __restrict__ wsrc,
                                                      const float* __restrict__ attn,
                                                      float* __restrict__ out) {
    __shared__ __align__(16) float xs[8][3][72];
    __shared__ __align__(16) float wsh[64 * 100];

    const int h   = blockIdx.x;
    const int ob  = blockIdx.y * 64;
    const int b   = blockIdx.z;
    const int tid = threadIdx.x;
    const int o_idx = tid >> 4;
    const int w0    = (tid & 15) * 4;

    float a0 = 0.f, a1 = 0.f, a2 = 0.f, a3 = 0.f;
    if (OTF) {
        a0 = attn[b * 4 + 0]; a1 = attn[b * 4 + 1];
        a2 = attn[b * 4 + 2]; a3 = attn[b * 4 + 3];
    }
    const float* xb = x + (size_t)b * (C_ * HW_);
    const float* wb = OTF ? (wsrc + (size_t)ob * 2304)
                          : (wsrc + (size_t)b * WPERK + (size_t)ob * 2304);
    float acc[4][4];
#pragma unroll
    for (int i = 0; i < 4; ++i)
#pragma unroll
        for (int j = 0; j < 4; ++j) acc[i][j] = 0.f;

    for (int cb = 0; cb < C_; cb += 8) {
        __syncthreads();
        for (int idx = tid; idx < 8 * 3 * 66; idx += 256) {
            int c = idx / 198, rem = idx - c * 198;
            int r = rem / 66, wi = rem - r * 66;
            int hh = h - 1 + r, ww = wi - 1;
            float v = 0.f;
            if ((unsigned)hh < 64u && (unsigned)ww < 64u)
                v = xb[(size_t)(cb + c) * HW_ + hh * 64 + ww];
            xs[c][r][wi] = v;
        }
        for (int idx = tid; idx < 64 * 72; idx += 256) {
            int o = idx / 72, j = idx - o * 72;
            int c = j / 9, t = j - c * 9;
            size_t gi = (size_t)o * 2304 + (size_t)(cb + c) * 9 + t;
            float v;
            if (OTF)
                v = a0 * wb[gi] + a1 * wb[WPERK + gi] +
                    a2 * wb[2 * WPERK + gi] + a3 * wb[3 * WPERK + gi];
            else
                v = wb[gi];
            wsh[o * 100 + c * 12 + t] = v;
        }
        __syncthreads();
#pragma unroll
        for (int cc = 0; cc < 8; ++cc) {
            float xr[3][6];
#pragma unroll
            for (int r = 0; r < 3; ++r) {
                float4 a = *(const float4*)&xs[cc][r][w0];
                float2 b2 = *(const float2*)&xs[cc][r][w0 + 4];
                xr[r][0] = a.x; xr[r][1] = a.y; xr[r][2] = a.z; xr[r][3] = a.w;
                xr[r][4] = b2.x; xr[r][5] = b2.y;
            }
#pragma unroll
            for (int oo = 0; oo < 4; ++oo) {
                const float* wp = &wsh[(o_idx * 4 + oo) * 100 + cc * 12];
                float4 wA = *(const float4*)wp;
                float4 wB = *(const float4*)(wp + 4);
                float w8 = wp[8];
#pragma unroll
                for (int ww = 0; ww < 4; ++ww) {
                    acc[oo][ww] += wA.x * xr[0][ww]     + wA.y * xr[0][ww + 1] + wA.z * xr[0][ww + 2]
                                 + wA.w * xr[1][ww]     + wB.x * xr[1][ww + 1] + wB.y * xr[1][ww + 2]
                                 + wB.z * xr[2][ww]     + wB.w * xr[2][ww + 1] + w8   * xr[2][ww + 2];
                }
            }
        }
    }
    float* op = out + ((size_t)b * O_ + ob) * HW_ + h * 64;
#pragma unroll
    for (int oo = 0; oo < 4; ++oo) {
        float4 v = make_float4(acc[oo][0], acc[oo][1], acc[oo][2], acc[oo][3]);
        *(float4*)&op[(size_t)(o_idx * 4 + oo) * HW_ + w0] = v;
    }
}

// ---------------- BN stats ----------------
__global__ __launch_bounds__(256) void stats_kernel(const float4* __restrict__ out4,
                                                    const float* __restrict__ gamma,
                                                    float* __restrict__ mean,
                                                    float* __restrict__ inv) {
    int o = blockIdx.x;
    float s = 0.f, s2 = 0.f;
    for (int b = 0; b < B_; ++b) {
        const float4* p = out4 + ((size_t)b * O_ + o) * PLANE_F4;
        for (int i = threadIdx.x; i < PLANE_F4; i += 256) {
            float4 v = p[i];
            s  += v.x + v.y + v.z + v.w;
            s2 += v.x * v.x + v.y * v.y + v.z * v.z + v.w * v.w;
        }
    }
    for (int off = 32; off; off >>= 1) {
        s  += __shfl_down(s, off);
        s2 += __shfl_down(s2, off);
    }
    __shared__ float ps[4], ps2[4];
    int w = threadIdx.x >> 6;
    if ((threadIdx.x & 63) == 0) { ps[w] = s; ps2[w] = s2; }
    __syncthreads();
    if (threadIdx.x == 0) {
        float S = ps[0] + ps[1] + ps[2] + ps[3];
        float S2 = ps2[0] + ps2[1] + ps2[2] + ps2[3];
        float m = S * (1.f / 65536.f);
        float var = S2 * (1.f / 65536.f) - m * m;
        mean[o] = m;
        inv[o] = gamma[o] * rsqrtf(var + 1e-3f);
    }
}

// ---------------- BN apply + SiLU ----------------
__global__ __launch_bounds__(256) void bn_silu_kernel(float4* __restrict__ out4,
                                                      const float* __restrict__ mean,
                                                      const float* __restrict__ inv,
                                                      const float* __restrict__ beta) {
    const int total = B_ * O_ * PLANE_F4;
    for (int i = blockIdx.x * 256 + threadIdx.x; i < total; i += gridDim.x * 256) {
        int plane = i >> 10;
        int o = plane & 255;
        float m = mean[o], iv = inv[o], bt = beta[o];
        float4 v = out4[i];
        float u;
        u = (v.x - m) * iv + bt; v.x = u / (1.f + expf(-u));
        u = (v.y - m) * iv + bt; v.y = u / (1.f + expf(-u));
        u = (v.z - m) * iv + bt; v.z = u / (1.f + expf(-u));
        u = (v.w - m) * iv + bt; v.w = u / (1.f + expf(-u));
        out4[i] = v;
    }
}

extern "C" void kernel_launch(void* const* d_in, const int* in_sizes, int n_in,
                              void* d_out, int out_size, void* d_ws, size_t ws_size,
                              hipStream_t stream) {
    const float* x      = (const float*)d_in[0];
    const float* dyn    = (const float*)d_in[1];
    const float* attn_w = (const float*)d_in[2];
    const float* gamma  = (const float*)d_in[3];
    const float* beta   = (const float*)d_in[4];
    float* out = (float*)d_out;
    float* ws  = (float*)d_ws;

    float* pooled = ws;             // 4096
    float* attn   = ws + 4096;      // 64
    float* mean   = ws + 4160;      // 256
    float* inv    = ws + 4416;      // 256
    unsigned short* wt_hi = (unsigned short*)(ws + 4672);   // 9437184 bf16
    unsigned short* wt_lo = wt_hi + 9437184;                // 9437184 bf16

    const size_t needed = (size_t)4672 * 4 + 2ull * 9437184ull * 2ull;  // 37,767,424 B
    const bool mfma_path = ws_size >= needed;

    pool_kernel<<<4096, 256, 0, stream>>>((const float4*)x, pooled);
    attn_kernel<<<1, 64, 0, stream>>>(pooled, attn_w, attn);
    if (mfma_path) {
        wtrans_kernel<<<4096, 256, 0, stream>>>(dyn, attn, wt_hi, wt_lo);
        conv_mfma_kernel<<<dim3(32, 2, 16), 256, 0, stream>>>(x, wt_hi, wt_lo, out);
    } else {
        conv_kernel<true><<<dim3(64, 4, 16), 256, 0, stream>>>(x, dyn, attn, out);
    }
    stats_kernel<<<256, 256, 0, stream>>>((const float4*)out, gamma, mean, inv);
    bn_silu_kernel<<<4096, 256, 0, stream>>>((float4*)out, mean, inv, beta);
}

// Round 3
// 449.988 us; speedup vs baseline: 4.5858x; 1.1526x over previous
//
#include <hip/hip_runtime.h>
#include <math.h>

// DynamicConv on MI355X — round 3: 32x32x16 MFMA conv + async-stage (T14) +
// per-tap A-hoist + XCD swizzle; 2-stage BN stats.
// conv-as-GEMM per batch: M=256(o), N=4096(hw), K=2304(c*9), split bf16 hi/lo,
// 3 MFMA passes (hh,hl,lh). MFMA floor ~93us; target 130-170us (was 374).

#define B_ 16
#define C_ 256
#define O_ 256
#define HW_ 4096          // 64*64
#define PLANE_F4 1024
#define WPERK 589824      // O_*C_*9
#define XS_PX 40          // bf16 slots per pixel in LDS x tile (32 ch + 8 pad)

typedef short bf16x8 __attribute__((ext_vector_type(8)));
typedef float f32x16 __attribute__((ext_vector_type(16)));

__device__ __forceinline__ unsigned short f2bf(float f) {
    unsigned u = __float_as_uint(f);
    u += 0x7FFFu + ((u >> 16) & 1u);
    return (unsigned short)(u >> 16);
}
__device__ __forceinline__ float bf2f(unsigned short h) {
    return __uint_as_float((unsigned)h << 16);
}

// ---------------- pool ----------------
__global__ __launch_bounds__(256) void pool_kernel(const float4* __restrict__ x4,
                                                   float* __restrict__ pooled) {
    int bc = blockIdx.x;
    const float4* p = x4 + (size_t)bc * PLANE_F4;
    float s = 0.f;
    for (int i = threadIdx.x; i < PLANE_F4; i += 256) {
        float4 v = p[i];
        s += v.x + v.y + v.z + v.w;
    }
    for (int off = 32; off; off >>= 1) s += __shfl_down(s, off);
    __shared__ float partial[4];
    if ((threadIdx.x & 63) == 0) partial[threadIdx.x >> 6] = s;
    __syncthreads();
    if (threadIdx.x == 0)
        pooled[bc] = (partial[0] + partial[1] + partial[2] + partial[3]) * (1.f / 4096.f);
}

// ---------------- attn ----------------
__global__ void attn_kernel(const float* __restrict__ pooled,
                            const float* __restrict__ attn_w,
                            float* __restrict__ attn) {
    int tid = threadIdx.x;                     // 64 threads
    int b = tid >> 2, k = tid & 3;
    float s = 0.f;
    for (int c = 0; c < C_; ++c) s += pooled[b * C_ + c] * attn_w[k * C_ + c];
    __shared__ float lg[16][4];
    lg[b][k] = s;
    __syncthreads();
    float m = fmaxf(fmaxf(lg[b][0], lg[b][1]), fmaxf(lg[b][2], lg[b][3]));
    float den = expf(lg[b][0] - m) + expf(lg[b][1] - m) +
                expf(lg[b][2] - m) + expf(lg[b][3] - m);
    attn[tid] = expf(s - m) / den;
}

// ---------------- wtrans: combine, split hi/lo, transpose to [b][o][t][c] ----------------
__global__ __launch_bounds__(256) void wtrans_kernel(const float* __restrict__ dyn,
                                                     const float* __restrict__ attn,
                                                     unsigned short* __restrict__ wt_hi,
                                                     unsigned short* __restrict__ wt_lo) {
    int idx = blockIdx.x * 256 + threadIdx.x;   // (b,o,c)
    int b = idx >> 16;
    int o = (idx >> 8) & 255;
    int c = idx & 255;
    float a0 = attn[b * 4 + 0], a1 = attn[b * 4 + 1],
          a2 = attn[b * 4 + 2], a3 = attn[b * 4 + 3];
    const float* p0 = dyn + ((size_t)o * 256 + c) * 9;
    float v[9];
#pragma unroll
    for (int t = 0; t < 9; ++t)
        v[t] = a0 * p0[t] + a1 * p0[WPERK + t] + a2 * p0[2 * WPERK + t] + a3 * p0[3 * WPERK + t];
    size_t obase = ((size_t)(b * 256 + o) * 9) * 256 + c;
#pragma unroll
    for (int t = 0; t < 9; ++t) {
        float f = v[t];
        unsigned short h = f2bf(f);
        unsigned short l = f2bf(f - bf2f(h));
        wt_hi[obase + (size_t)t * 256] = h;
        wt_lo[obase + (size_t)t * 256] = l;
    }
}

// ---------------- conv via 32x32x16 MFMA ----------------
// 1024 blocks (XCD-swizzled), 256 thr = 4 waves. WG tile 128o x 128px (2 rows).
// wave = 64o x 64px(1 row): 2x2 frags of 32x32. K loop: 8 chunks of 32c x 9 taps.
__global__ __launch_bounds__(256, 2) void conv_mfma_kernel(const float* __restrict__ x,
        const unsigned short* __restrict__ wt_hi,
        const unsigned short* __restrict__ wt_lo,
        float* __restrict__ out) {
    __shared__ __align__(16) unsigned short xs_hi[4 * 66 * XS_PX];
    __shared__ __align__(16) unsigned short xs_lo[4 * 66 * XS_PX];

    // XCD swizzle: consecutive work chunks per XCD -> each XCD owns 2 batches
    const int bid = blockIdx.x;                 // 0..1023
    const int swz = (bid & 7) * 128 + (bid >> 3);
    const int b  = swz >> 6;
    const int ob = (swz >> 5) & 1;
    const int hp = swz & 31;
    const int h0 = hp * 2;

    const int tid  = threadIdx.x;
    const int lane = tid & 63;
    const int wid  = tid >> 6;
    const int l31  = lane & 31;
    const int g2   = lane >> 5;
    const int wo   = ob * 128 + (wid >> 1) * 64;   // wave o-base
    const int wrow = wid & 1;                      // wave row within pair
    const int hr   = h0 + wrow;

    // staging role: row = wid (0..3 -> h0-1..h0+2), px = lane
    const int sr = wid;
    const int sw = lane;
    const int hh = h0 - 1 + sr;
    const bool hvalid = (unsigned)hh < 64u;        // wave-uniform
    const float* xsrc = x + (size_t)b * (C_ * HW_) + (size_t)(hvalid ? hh : 0) * 64 + sw;
    unsigned short* sh_hi = &xs_hi[(sr * 66 + sw + 1) * XS_PX];
    unsigned short* sh_lo = &xs_lo[(sr * 66 + sw + 1) * XS_PX];

    // zero the w-halo slots (px = -1 and 64 of each row) once
    if (tid < 8) {
        int r = tid >> 1;
        int slot = r * 66 + ((tid & 1) ? 65 : 0);
        uint4 z = make_uint4(0u, 0u, 0u, 0u);
#pragma unroll
        for (int u = 0; u < 4; ++u) {
            *(uint4*)&xs_hi[slot * XS_PX + u * 8] = z;
            *(uint4*)&xs_lo[slot * XS_PX + u * 8] = z;
        }
    }

    f32x16 acc[2][2];
#pragma unroll
    for (int i = 0; i < 2; ++i)
#pragma unroll
        for (int j = 0; j < 2; ++j) acc[i][j] = (f32x16)(0.f);

    // per-thread MFMA operand bases
    const unsigned short* wbh = wt_hi + ((size_t)(b * 256 + wo + l31) * 9) * 256 + g2 * 8;
    const unsigned short* wbl = wt_lo + ((size_t)(b * 256 + wo + l31) * 9) * 256 + g2 * 8;
    const unsigned short* xph = xs_hi + (wrow * 66 + l31) * XS_PX + g2 * 8;
    const unsigned short* xpl = xs_lo + (wrow * 66 + l31) * XS_PX + g2 * 8;

#define LOADX(buf, cb) do {                                              \
        const float* _p = xsrc + (size_t)(cb) * HW_;                     \
        if (hvalid) {                                                    \
            _Pragma("unroll")                                            \
            for (int _c = 0; _c < 32; ++_c) buf[_c] = _p[(size_t)_c * HW_]; \
        } else {                                                         \
            _Pragma("unroll")                                            \
            for (int _c = 0; _c < 32; ++_c) buf[_c] = 0.f;               \
        }                                                                \
    } while (0)

#define STOREX(buf) do {                                                 \
        unsigned _hw[16], _lw[16];                                       \
        _Pragma("unroll")                                                \
        for (int _c = 0; _c < 16; ++_c) {                                \
            unsigned short h0_ = f2bf(buf[2 * _c]);                      \
            unsigned short l0_ = f2bf(buf[2 * _c] - bf2f(h0_));          \
            unsigned short h1_ = f2bf(buf[2 * _c + 1]);                  \
            unsigned short l1_ = f2bf(buf[2 * _c + 1] - bf2f(h1_));      \
            _hw[_c] = (unsigned)h0_ | ((unsigned)h1_ << 16);             \
            _lw[_c] = (unsigned)l0_ | ((unsigned)l1_ << 16);             \
        }                                                                \
        _Pragma("unroll")                                                \
        for (int _u = 0; _u < 4; ++_u) {                                 \
            *(uint4*)&sh_hi[_u * 8] = make_uint4(_hw[4*_u], _hw[4*_u+1], _hw[4*_u+2], _hw[4*_u+3]); \
            *(uint4*)&sh_lo[_u * 8] = make_uint4(_lw[4*_u], _lw[4*_u+1], _lw[4*_u+2], _lw[4*_u+3]); \
        }                                                                \
    } while (0)

#define MFMA_CHUNK(cb) do {                                              \
        _Pragma("unroll")                                                \
        for (int t = 0; t < 9; ++t) {                                    \
            const int dh = t / 3, dw = t % 3;                            \
            bf16x8 bh_[2][2], bl_[2][2];                                 \
            _Pragma("unroll")                                            \
            for (int ks = 0; ks < 2; ++ks)                               \
                _Pragma("unroll")                                        \
                for (int nf = 0; nf < 2; ++nf) {                         \
                    const int xoff = (dh * 66 + dw + nf * 32) * XS_PX + ks * 16; \
                    bh_[ks][nf] = *(const bf16x8*)&xph[xoff];            \
                    bl_[ks][nf] = *(const bf16x8*)&xpl[xoff];            \
                }                                                        \
            bf16x8 ah_[2][2], al_[2][2];                                 \
            _Pragma("unroll")                                            \
            for (int mf = 0; mf < 2; ++mf)                               \
                _Pragma("unroll")                                        \
                for (int ks = 0; ks < 2; ++ks) {                         \
                    const size_t woff = (size_t)mf * 73728 + (size_t)t * 256 + ks * 16 + (cb); \
                    ah_[mf][ks] = *(const bf16x8*)(wbh + woff);          \
                    al_[mf][ks] = *(const bf16x8*)(wbl + woff);          \
                }                                                        \
            _Pragma("unroll")                                            \
            for (int mf = 0; mf < 2; ++mf)                               \
                _Pragma("unroll")                                        \
                for (int ks = 0; ks < 2; ++ks)                           \
                    _Pragma("unroll")                                    \
                    for (int nf = 0; nf < 2; ++nf)                       \
                        acc[mf][nf] = __builtin_amdgcn_mfma_f32_32x32x16_bf16(ah_[mf][ks], bh_[ks][nf], acc[mf][nf], 0, 0, 0); \
            _Pragma("unroll")                                            \
            for (int mf = 0; mf < 2; ++mf)                               \
                _Pragma("unroll")                                        \
                for (int ks = 0; ks < 2; ++ks)                           \
                    _Pragma("unroll")                                    \
                    for (int nf = 0; nf < 2; ++nf)                       \
                        acc[mf][nf] = __builtin_amdgcn_mfma_f32_32x32x16_bf16(ah_[mf][ks], bl_[ks][nf], acc[mf][nf], 0, 0, 0); \
            _Pragma("unroll")                                            \
            for (int mf = 0; mf < 2; ++mf)                               \
                _Pragma("unroll")                                        \
                for (int ks = 0; ks < 2; ++ks)                           \
                    _Pragma("unroll")                                    \
                    for (int nf = 0; nf < 2; ++nf)                       \
                        acc[mf][nf] = __builtin_amdgcn_mfma_f32_32x32x16_bf16(al_[mf][ks], bh_[ks][nf], acc[mf][nf], 0, 0, 0); \
        }                                                                \
    } while (0)

    float xa[32], xb2[32];
    LOADX(xa, 0);
#pragma unroll 1
    for (int cc = 0; cc < 256; cc += 64) {
        // chunk cc (buf xa)
        __syncthreads();
        STOREX(xa);
        __syncthreads();
        LOADX(xb2, cc + 32);             // T14: issue next-chunk loads before MFMA
        MFMA_CHUNK(cc);
        // chunk cc+32 (buf xb2)
        __syncthreads();
        STOREX(xb2);
        __syncthreads();
        if (cc + 64 < 256) LOADX(xa, cc + 64);
        MFMA_CHUNK(cc + 32);
    }

    // epilogue: C layout (32x32): col=lane&31 (px), row=(r&3)+8*(r>>2)+4*(lane>>5)
    float* op = out + ((size_t)b * 256 + wo) * HW_ + (size_t)hr * 64;
#pragma unroll
    for (int mf = 0; mf < 2; ++mf)
#pragma unroll
        for (int nf = 0; nf < 2; ++nf) {
            f32x16 a = acc[mf][nf];
#pragma unroll
            for (int r = 0; r < 16; ++r) {
                int row = (r & 3) + 8 * (r >> 2) + 4 * g2;
                op[(size_t)(mf * 32 + row) * HW_ + nf * 32 + l31] = a[r];
            }
        }
#undef LOADX
#undef STOREX
#undef MFMA_CHUNK
}

// ---------------- fp32 OTF conv fallback (ws too small) ----------------
__global__ __launch_bounds__(256, 2) void conv_otf_kernel(const float* __restrict__ x,
                                                          const float* __restrict__ wsrc,
                                                          const float* __restrict__ attn,
                                                          float* __restrict__ out) {
    __shared__ __align__(16) float xs[8][3][72];
    __shared__ __align__(16) float wsh[64 * 100];
    const int h   = blockIdx.x;
    const int ob  = blockIdx.y * 64;
    const int b   = blockIdx.z;
    const int tid = threadIdx.x;
    const int o_idx = tid >> 4;
    const int w0    = (tid & 15) * 4;
    float a0 = attn[b * 4 + 0], a1 = attn[b * 4 + 1],
          a2 = attn[b * 4 + 2], a3 = attn[b * 4 + 3];
    const float* xb = x + (size_t)b * (C_ * HW_);
    const float* wb = wsrc + (size_t)ob * 2304;
    float acc[4][4];
#pragma unroll
    for (int i = 0; i < 4; ++i)
#pragma unroll
        for (int j = 0; j < 4; ++j) acc[i][j] = 0.f;
    for (int cb = 0; cb < C_; cb += 8) {
        __syncthreads();
        for (int idx = tid; idx < 8 * 3 * 66; idx += 256) {
            int c = idx / 198, rem = idx - c * 198;
            int r = rem / 66, wi = rem - r * 66;
            int hhh = h - 1 + r, ww = wi - 1;
            float v = 0.f;
            if ((unsigned)hhh < 64u && (unsigned)ww < 64u)
                v = xb[(size_t)(cb + c) * HW_ + hhh * 64 + ww];
            xs[c][r][wi] = v;
        }
        for (int idx = tid; idx < 64 * 72; idx += 256) {
            int o = idx / 72, j = idx - o * 72;
            int c = j / 9, t = j - c * 9;
            size_t gi = (size_t)o * 2304 + (size_t)(cb + c) * 9 + t;
            float v = a0 * wb[gi] + a1 * wb[WPERK + gi] +
                      a2 * wb[2 * WPERK + gi] + a3 * wb[3 * WPERK + gi];
            wsh[o * 100 + c * 12 + t] = v;
        }
        __syncthreads();
#pragma unroll
        for (int cc = 0; cc < 8; ++cc) {
            float xr[3][6];
#pragma unroll
            for (int r = 0; r < 3; ++r) {
                float4 a = *(const float4*)&xs[cc][r][w0];
                float2 b2 = *(const float2*)&xs[cc][r][w0 + 4];
                xr[r][0] = a.x; xr[r][1] = a.y; xr[r][2] = a.z; xr[r][3] = a.w;
                xr[r][4] = b2.x; xr[r][5] = b2.y;
            }
#pragma unroll
            for (int oo = 0; oo < 4; ++oo) {
                const float* wp = &wsh[(o_idx * 4 + oo) * 100 + cc * 12];
                float4 wA = *(const float4*)wp;
                float4 wB = *(const float4*)(wp + 4);
                float w8 = wp[8];
#pragma unroll
                for (int ww = 0; ww < 4; ++ww) {
                    acc[oo][ww] += wA.x * xr[0][ww]     + wA.y * xr[0][ww + 1] + wA.z * xr[0][ww + 2]
                                 + wA.w * xr[1][ww]     + wB.x * xr[1][ww + 1] + wB.y * xr[1][ww + 2]
                                 + wB.z * xr[2][ww]     + wB.w * xr[2][ww + 1] + w8   * xr[2][ww + 2];
                }
            }
        }
    }
    float* op = out + ((size_t)b * O_ + ob) * HW_ + h * 64;
#pragma unroll
    for (int oo = 0; oo < 4; ++oo) {
        float4 v = make_float4(acc[oo][0], acc[oo][1], acc[oo][2], acc[oo][3]);
        *(float4*)&op[(size_t)(o_idx * 4 + oo) * HW_ + w0] = v;
    }
}

// ---------------- BN stats: stage 1 (per b,o plane partial) ----------------
__global__ __launch_bounds__(256) void stats1_kernel(const float4* __restrict__ out4,
                                                     float* __restrict__ psum,
                                                     float* __restrict__ psumsq) {
    int bo = blockIdx.x;                           // b*256+o
    const float4* p = out4 + (size_t)bo * PLANE_F4;
    float s = 0.f, s2 = 0.f;
    for (int i = threadIdx.x; i < PLANE_F4; i += 256) {
        float4 v = p[i];
        s  += v.x + v.y + v.z + v.w;
        s2 += v.x * v.x + v.y * v.y + v.z * v.z + v.w * v.w;
    }
    for (int off = 32; off; off >>= 1) {
        s  += __shfl_down(s, off);
        s2 += __shfl_down(s2, off);
    }
    __shared__ float ps[4], ps2[4];
    int w = threadIdx.x >> 6;
    if ((threadIdx.x & 63) == 0) { ps[w] = s; ps2[w] = s2; }
    __syncthreads();
    if (threadIdx.x == 0) {
        psum[bo]   = ps[0] + ps[1] + ps[2] + ps[3];
        psumsq[bo] = ps2[0] + ps2[1] + ps2[2] + ps2[3];
    }
}

// ---------------- BN stats: stage 2 (reduce over b) ----------------
__global__ __launch_bounds__(256) void stats2_kernel(const float* __restrict__ psum,
                                                     const float* __restrict__ psumsq,
                                                     const float* __restrict__ gamma,
                                                     float* __restrict__ mean,
                                                     float* __restrict__ inv) {
    int o = threadIdx.x;
    float S = 0.f, S2 = 0.f;
#pragma unroll
    for (int b = 0; b < B_; ++b) {
        S  += psum[b * 256 + o];
        S2 += psumsq[b * 256 + o];
    }
    float m = S * (1.f / 65536.f);
    float var = S2 * (1.f / 65536.f) - m * m;
    mean[o] = m;
    inv[o] = gamma[o] * rsqrtf(var + 1e-3f);
}

// ---------------- BN apply + SiLU ----------------
__global__ __launch_bounds__(256) void bn_silu_kernel(float4* __restrict__ out4,
                                                      const float* __restrict__ mean,
                                                      const float* __restrict__ inv,
                                                      const float* __restrict__ beta) {
    const int total = B_ * O_ * PLANE_F4;
    for (int i = blockIdx.x * 256 + threadIdx.x; i < total; i += gridDim.x * 256) {
        int plane = i >> 10;
        int o = plane & 255;
        float m = mean[o], iv = inv[o], bt = beta[o];
        float4 v = out4[i];
        float u;
        u = (v.x - m) * iv + bt; v.x = u / (1.f + expf(-u));
        u = (v.y - m) * iv + bt; v.y = u / (1.f + expf(-u));
        u = (v.z - m) * iv + bt; v.z = u / (1.f + expf(-u));
        u = (v.w - m) * iv + bt; v.w = u / (1.f + expf(-u));
        out4[i] = v;
    }
}

extern "C" void kernel_launch(void* const* d_in, const int* in_sizes, int n_in,
                              void* d_out, int out_size, void* d_ws, size_t ws_size,
                              hipStream_t stream) {
    const float* x      = (const float*)d_in[0];
    const float* dyn    = (const float*)d_in[1];
    const float* attn_w = (const float*)d_in[2];
    const float* gamma  = (const float*)d_in[3];
    const float* beta   = (const float*)d_in[4];
    float* out = (float*)d_out;
    float* ws  = (float*)d_ws;

    float* pooled = ws;             // 4096
    float* attn   = ws + 4096;      // 64
    float* mean   = ws + 4160;      // 256
    float* inv    = ws + 4416;      // 256
    unsigned short* wt_hi = (unsigned short*)(ws + 4672);   // 9437184 bf16
    unsigned short* wt_lo = wt_hi + 9437184;                // 9437184 bf16
    // stats partials reuse the weight area (weights dead after conv)
    float* psum   = (float*)wt_hi;  // 4096
    float* psumsq = psum + 4096;    // 4096

    const size_t needed = (size_t)4672 * 4 + 2ull * 9437184ull * 2ull;  // 37,767,424 B
    const bool mfma_path = ws_size >= needed;

    pool_kernel<<<4096, 256, 0, stream>>>((const float4*)x, pooled);
    attn_kernel<<<1, 64, 0, stream>>>(pooled, attn_w, attn);
    if (mfma_path) {
        wtrans_kernel<<<4096, 256, 0, stream>>>(dyn, attn, wt_hi, wt_lo);
        conv_mfma_kernel<<<1024, 256, 0, stream>>>(x, wt_hi, wt_lo, out);
    } else {
        conv_otf_kernel<<<dim3(64, 4, 16), 256, 0, stream>>>(x, dyn, attn, out);
    }
    stats1_kernel<<<4096, 256, 0, stream>>>((const float4*)out, psum, psumsq);
    stats2_kernel<<<1, 256, 0, stream>>>(psum, psumsq, gamma, mean, inv);
    bn_silu_kernel<<<4096, 256, 0, stream>>>((float4*)out, mean, inv, beta);
}